// Round 1
// baseline (145.036 us; speedup 1.0000x reference)
//
#include <hip/hip_runtime.h>

typedef __attribute__((ext_vector_type(4))) float f32x4;
typedef __attribute__((ext_vector_type(8))) __bf16 bf16x8;
typedef __attribute__((ext_vector_type(4))) unsigned short us4;
typedef __attribute__((ext_vector_type(8))) unsigned short us8;

#define DEVI static __device__ __forceinline__

constexpr int T_ = 2048, E_ = 1024, H_ = 16, D_ = 64;

DEVI unsigned short f2b(float f) {
  union { float fv; unsigned u; } c; c.fv = f;
  unsigned r = c.u + 0x7fffu + ((c.u >> 16) & 1u);
  return (unsigned short)(r >> 16);
}

DEVI f32x4 mfma16(bf16x8 a, bf16x8 b, f32x4 c) {
  return __builtin_amdgcn_mfma_f32_16x16x32_bf16(a, b, c, 0, 0, 0);
}

// ---------------- QKV projection ----------------
// grid: (B*H=32, T/256=8), block 256
__launch_bounds__(256)
__global__ void qkv_kernel(const float* __restrict__ x,
                           const float* __restrict__ Wq, const float* __restrict__ bq,
                           const float* __restrict__ Wk, const float* __restrict__ bk,
                           const float* __restrict__ Wv, const float* __restrict__ bv,
                           unsigned short* __restrict__ qo,
                           unsigned short* __restrict__ ko,
                           unsigned short* __restrict__ vto)
{
  const int bh = blockIdx.x;
  const int b  = bh >> 4;
  const int h  = bh & (H_ - 1);
  const int t0 = blockIdx.y * 256;
  __shared__ unsigned short Xl[256][72];
  __shared__ unsigned short Wl[3][64][72];
  const int tid = threadIdx.x;

  // stage X slice (256 x 64), f32 -> bf16
  #pragma unroll
  for (int p = 0; p < 16; ++p) {
    int idx = p * 256 + tid;
    int row = idx >> 4, c4 = idx & 15;
    const float* gp = x + ((size_t)(b * T_ + t0 + row)) * E_ + h * 64 + c4 * 4;
    float4 v = *(const float4*)gp;
    us4 o; o[0] = f2b(v.x); o[1] = f2b(v.y); o[2] = f2b(v.z); o[3] = f2b(v.w);
    *(us4*)&Xl[row][c4 * 4] = o;
  }
  // stage W blocks for this head (64 x 64 each); Wq pre-scaled by 1/8
  #pragma unroll
  for (int p = 0; p < 4; ++p) {
    int idx = p * 256 + tid;
    int row = idx >> 4, c4 = idx & 15;
    {
      float4 v = *(const float4*)(Wq + (size_t)(h * 64 + row) * 64 + c4 * 4);
      us4 o; o[0] = f2b(v.x * 0.125f); o[1] = f2b(v.y * 0.125f);
      o[2] = f2b(v.z * 0.125f); o[3] = f2b(v.w * 0.125f);
      *(us4*)&Wl[0][row][c4 * 4] = o;
    }
    {
      float4 v = *(const float4*)(Wk + (size_t)(h * 64 + row) * 64 + c4 * 4);
      us4 o; o[0] = f2b(v.x); o[1] = f2b(v.y); o[2] = f2b(v.z); o[3] = f2b(v.w);
      *(us4*)&Wl[1][row][c4 * 4] = o;
    }
    {
      float4 v = *(const float4*)(Wv + (size_t)(h * 64 + row) * 64 + c4 * 4);
      us4 o; o[0] = f2b(v.x); o[1] = f2b(v.y); o[2] = f2b(v.z); o[3] = f2b(v.w);
      *(us4*)&Wl[2][row][c4 * 4] = o;
    }
  }
  __syncthreads();

  const int w = tid >> 6, lane = tid & 63, lo = lane & 15, g = lane >> 4;
  const int tl0 = w * 64;

  // X B-fragments (used as B for Q/K transposed products)
  bf16x8 xb[4][2];
  #pragma unroll
  for (int tt = 0; tt < 4; ++tt)
    #pragma unroll
    for (int kd = 0; kd < 2; ++kd)
      xb[tt][kd] = *(const bf16x8*)&Xl[tl0 + tt * 16 + lo][kd * 32 + g * 8];

  // Q and K: C = W * X^T  (o x t); store row-major q[t][o] with packed 4-d stores
  #pragma unroll
  for (int tsel = 0; tsel < 2; ++tsel) {
    const float* bias = tsel ? bk : bq;
    unsigned short* outp = tsel ? ko : qo;
    const float bs = tsel ? 1.0f : 0.125f;
    #pragma unroll
    for (int ot = 0; ot < 4; ++ot) {
      bf16x8 a0 = *(const bf16x8*)&Wl[tsel][ot * 16 + lo][g * 8];
      bf16x8 a1 = *(const bf16x8*)&Wl[tsel][ot * 16 + lo][32 + g * 8];
      float4 bv4 = *(const float4*)(bias + h * 64 + ot * 16 + g * 4);
      float bb[4] = {bv4.x * bs, bv4.y * bs, bv4.z * bs, bv4.w * bs};
      #pragma unroll
      for (int tt = 0; tt < 4; ++tt) {
        f32x4 acc = {0.f, 0.f, 0.f, 0.f};
        acc = mfma16(a0, xb[tt][0], acc);
        acc = mfma16(a1, xb[tt][1], acc);
        int tg = t0 + tl0 + tt * 16 + lo;
        us4 pk;
        #pragma unroll
        for (int r = 0; r < 4; ++r) pk[r] = f2b(acc[r] + bb[r]);
        *(us4*)(outp + ((size_t)(bh * T_ + tg)) * 64 + ot * 16 + g * 4) = pk;
      }
    }
  }

  // V: C = X * W^T (t x o); store transposed vt[(bh*64+d)*T + t] packed over t
  #pragma unroll
  for (int rt = 0; rt < 4; ++rt) {
    bf16x8 a0 = *(const bf16x8*)&Xl[tl0 + rt * 16 + lo][g * 8];
    bf16x8 a1 = *(const bf16x8*)&Xl[tl0 + rt * 16 + lo][32 + g * 8];
    #pragma unroll
    for (int ct = 0; ct < 4; ++ct) {
      bf16x8 b0 = *(const bf16x8*)&Wl[2][ct * 16 + lo][g * 8];
      bf16x8 b1 = *(const bf16x8*)&Wl[2][ct * 16 + lo][32 + g * 8];
      f32x4 acc = {0.f, 0.f, 0.f, 0.f};
      acc = mfma16(a0, b0, acc);
      acc = mfma16(a1, b1, acc);
      int d = ct * 16 + lo;
      float bvs = bv[h * 64 + d];
      int tg = t0 + tl0 + rt * 16 + g * 4;
      us4 pk;
      #pragma unroll
      for (int r = 0; r < 4; ++r) pk[r] = f2b(acc[r] + bvs);
      *(us4*)(vto + ((size_t)(bh * 64 + d)) * T_ + tg) = pk;
    }
  }
}

// ---------------- causal flash attention ----------------
// grid: (T/128=16, B*H=32), block 256 (4 waves x 32 q-rows)
__launch_bounds__(256)
__global__ void flash_kernel(const unsigned short* __restrict__ q,
                             const unsigned short* __restrict__ kk_,
                             const unsigned short* __restrict__ vt,
                             unsigned short* __restrict__ ao)
{
  const int qt = blockIdx.x;
  const int bh = blockIdx.y;
  const int b = bh >> 4, h = bh & 15;
  const int t0 = qt * 128;
  __shared__ unsigned short Kl[64][72];
  __shared__ unsigned short Vl[64][72];
  __shared__ unsigned short Pl[4][32][72];
  const int tid = threadIdx.x, w = tid >> 6, lane = tid & 63, lo = lane & 15, g = lane >> 4;
  const int tw = t0 + w * 32;

  // Q fragments (pre-scaled by 1/8 in qkv): Q[t][d] rows
  bf16x8 qf[2][2];
  const unsigned short* qb = q + ((size_t)(bh * T_ + tw)) * 64;
  #pragma unroll
  for (int tt = 0; tt < 2; ++tt)
    #pragma unroll
    for (int kd = 0; kd < 2; ++kd)
      qf[tt][kd] = *(const bf16x8*)(qb + (size_t)(tt * 16 + lo) * 64 + kd * 32 + g * 8);

  float m_[2] = {-1e30f, -1e30f};
  float l_[2] = {0.f, 0.f};
  f32x4 zero4 = {0.f, 0.f, 0.f, 0.f};
  f32x4 oacc[4][2];
  #pragma unroll
  for (int dt = 0; dt < 4; ++dt)
    #pragma unroll
    for (int tt = 0; tt < 2; ++tt) oacc[dt][tt] = zero4;

  const int nsteps = (t0 + 128) >> 6;
  for (int stp = 0; stp < nsteps; ++stp) {
    const int s0 = stp * 64;
    __syncthreads();
    #pragma unroll
    for (int p = 0; p < 2; ++p) {
      int ii = p * 256 + tid;
      int row = ii >> 3, c8 = ii & 7;
      *(us8*)&Kl[row][c8 * 8] = *(const us8*)(kk_ + ((size_t)(bh * T_ + s0 + row)) * 64 + c8 * 8);
      *(us8*)&Vl[row][c8 * 8] = *(const us8*)(vt + ((size_t)(bh * 64 + row)) * T_ + s0 + c8 * 8);
    }
    __syncthreads();
    if (s0 <= tw + 31) {
      // S^T = K * Q^T : col = t (lane&15), row = s
      f32x4 sacc[4][2];
      #pragma unroll
      for (int ss = 0; ss < 4; ++ss)
        #pragma unroll
        for (int tt = 0; tt < 2; ++tt) sacc[ss][tt] = zero4;
      #pragma unroll
      for (int ss = 0; ss < 4; ++ss) {
        bf16x8 ka0 = *(const bf16x8*)&Kl[ss * 16 + lo][g * 8];
        bf16x8 ka1 = *(const bf16x8*)&Kl[ss * 16 + lo][32 + g * 8];
        #pragma unroll
        for (int tt = 0; tt < 2; ++tt) {
          sacc[ss][tt] = mfma16(ka0, qf[tt][0], sacc[ss][tt]);
          sacc[ss][tt] = mfma16(ka1, qf[tt][1], sacc[ss][tt]);
        }
      }
      if (s0 + 63 > tw) {  // diagonal step: causal mask
        #pragma unroll
        for (int ss = 0; ss < 4; ++ss)
          #pragma unroll
          for (int tt = 0; tt < 2; ++tt)
            #pragma unroll
            for (int r = 0; r < 4; ++r) {
              int sg = s0 + ss * 16 + g * 4 + r;
              int tg = tw + tt * 16 + lo;
              if (sg > tg) sacc[ss][tt][r] = -1e30f;
            }
      }
      // online softmax over s (per lane column t)
      #pragma unroll
      for (int tt = 0; tt < 2; ++tt) {
        float mx = -1e30f;
        #pragma unroll
        for (int ss = 0; ss < 4; ++ss)
          #pragma unroll
          for (int r = 0; r < 4; ++r) mx = fmaxf(mx, sacc[ss][tt][r]);
        mx = fmaxf(mx, __shfl_xor(mx, 16));
        mx = fmaxf(mx, __shfl_xor(mx, 32));
        float mn = fmaxf(m_[tt], mx);
        float corr = __expf(m_[tt] - mn);
        m_[tt] = mn;
        float sum = 0.f;
        #pragma unroll
        for (int ss = 0; ss < 4; ++ss) {
          us4 pk;
          #pragma unroll
          for (int r = 0; r < 4; ++r) {
            float pv = __expf(sacc[ss][tt][r] - mn);
            sum += pv;
            pk[r] = f2b(pv);
          }
          *(us4*)&Pl[w][tt * 16 + lo][ss * 16 + g * 4] = pk;
        }
        sum += __shfl_xor(sum, 16);
        sum += __shfl_xor(sum, 32);
        l_[tt] = l_[tt] * corr + sum;
        #pragma unroll
        for (int dt = 0; dt < 4; ++dt) oacc[dt][tt] *= corr;
      }
      // O^T += Vt * P^T
      #pragma unroll
      for (int kh = 0; kh < 2; ++kh) {
        bf16x8 va[4];
        #pragma unroll
        for (int dt = 0; dt < 4; ++dt)
          va[dt] = *(const bf16x8*)&Vl[dt * 16 + lo][kh * 32 + g * 8];
        #pragma unroll
        for (int tt = 0; tt < 2; ++tt) {
          bf16x8 pb = *(const bf16x8*)&Pl[w][tt * 16 + lo][kh * 32 + g * 8];
          #pragma unroll
          for (int dt = 0; dt < 4; ++dt)
            oacc[dt][tt] = mfma16(va[dt], pb, oacc[dt][tt]);
        }
      }
    }
  }
  // epilogue: ao[(b*T+t)*E + h*64 + d], packed over d
  #pragma unroll
  for (int tt = 0; tt < 2; ++tt) {
    float inv = 1.0f / l_[tt];
    int tg = tw + tt * 16 + lo;
    unsigned short* op = ao + ((size_t)(b * T_ + tg)) * E_ + h * 64;
    #pragma unroll
    for (int dt = 0; dt < 4; ++dt) {
      us4 pk;
      #pragma unroll
      for (int r = 0; r < 4; ++r) pk[r] = f2b(oacc[dt][tt][r] * inv);
      *(us4*)(op + dt * 16 + g * 4) = pk;
    }
  }
}

// ---------------- output projection: out = AO * Wp^T + bp ----------------
// grid: (4096/128=32, 1024/128=8), block 256 (2x2 waves of 64x64)
__launch_bounds__(256)
__global__ void proj_kernel(const unsigned short* __restrict__ ao,
                            const float* __restrict__ wp,
                            const float* __restrict__ bp,
                            float* __restrict__ out)
{
  const int m0 = blockIdx.x * 128;
  const int n0 = blockIdx.y * 128;
  __shared__ unsigned short Al[128][40];
  __shared__ unsigned short Bl[128][40];
  const int tid = threadIdx.x, w = tid >> 6, lane = tid & 63, lo = lane & 15, g = lane >> 4;
  const int wr = (w >> 1) * 64, wc = (w & 1) * 64;
  f32x4 zero4 = {0.f, 0.f, 0.f, 0.f};
  f32x4 acc[4][4];
  #pragma unroll
  for (int i = 0; i < 4; ++i)
    #pragma unroll
    for (int j = 0; j < 4; ++j) acc[i][j] = zero4;

  for (int k0 = 0; k0 < 1024; k0 += 32) {
    __syncthreads();
    #pragma unroll
    for (int p = 0; p < 2; ++p) {
      int ii = p * 256 + tid;
      int row = ii >> 2, c = ii & 3;
      *(us8*)&Al[row][c * 8] = *(const us8*)(ao + (size_t)(m0 + row) * 1024 + k0 + c * 8);
    }
    #pragma unroll
    for (int p = 0; p < 4; ++p) {
      int ii = p * 256 + tid;
      int row = ii >> 3, c4 = ii & 7;
      float4 v = *(const float4*)(wp + (size_t)(n0 + row) * 1024 + k0 + c4 * 4);
      us4 o; o[0] = f2b(v.x); o[1] = f2b(v.y); o[2] = f2b(v.z); o[3] = f2b(v.w);
      *(us4*)&Bl[row][c4 * 4] = o;
    }
    __syncthreads();
    bf16x8 af[4], bfr[4];
    #pragma unroll
    for (int i = 0; i < 4; ++i) af[i] = *(const bf16x8*)&Al[wr + i * 16 + lo][g * 8];
    #pragma unroll
    for (int j = 0; j < 4; ++j) bfr[j] = *(const bf16x8*)&Bl[wc + j * 16 + lo][g * 8];
    #pragma unroll
    for (int i = 0; i < 4; ++i)
      #pragma unroll
      for (int j = 0; j < 4; ++j)
        acc[i][j] = mfma16(af[i], bfr[j], acc[i][j]);
  }
  #pragma unroll
  for (int j = 0; j < 4; ++j) {
    int n = n0 + wc + j * 16 + lo;
    float bias = bp[n];
    #pragma unroll
    for (int i = 0; i < 4; ++i) {
      #pragma unroll
      for (int r = 0; r < 4; ++r)
        out[(size_t)(m0 + wr + i * 16 + g * 4 + r) * 1024 + n] = acc[i][j][r] + bias;
    }
  }
}

extern "C" void kernel_launch(void* const* d_in, const int* in_sizes, int n_in,
                              void* d_out, int out_size, void* d_ws, size_t ws_size,
                              hipStream_t stream)
{
  const float* x  = (const float*)d_in[0];
  // d_in[1] = uni_causal_mask (causal handled analytically)
  const float* Wq = (const float*)d_in[2];
  const float* bq = (const float*)d_in[3];
  const float* Wk = (const float*)d_in[4];
  const float* bk = (const float*)d_in[5];
  const float* Wv = (const float*)d_in[6];
  const float* bv = (const float*)d_in[7];
  const float* Wp = (const float*)d_in[8];
  const float* bp = (const float*)d_in[9];
  float* out = (float*)d_out;

  char* ws = (char*)d_ws;
  const size_t SZ = (size_t)2 * 16 * 2048 * 64 * 2;  // 8 MB per bf16 tensor
  unsigned short* q  = (unsigned short*)(ws);
  unsigned short* kb = (unsigned short*)(ws + SZ);
  unsigned short* vt = (unsigned short*)(ws + 2 * SZ);
  unsigned short* ao = (unsigned short*)(ws + 3 * SZ);

  qkv_kernel<<<dim3(32, 8), 256, 0, stream>>>(x, Wq, bq, Wk, bk, Wv, bv, q, kb, vt);
  flash_kernel<<<dim3(16, 32), 256, 0, stream>>>(q, kb, vt, ao);
  proj_kernel<<<dim3(32, 8), 256, 0, stream>>>(ao, Wp, bp, out);
}

// Round 3
// 122.921 us; speedup vs baseline: 1.1799x; 1.1799x over previous
//
#include <hip/hip_runtime.h>

typedef __attribute__((ext_vector_type(4))) float f32x4;
typedef __attribute__((ext_vector_type(8))) __bf16 bf16x8;
typedef __attribute__((ext_vector_type(4))) unsigned short us4;
typedef __attribute__((ext_vector_type(8))) unsigned short us8;

#define DEVI static __device__ __forceinline__

constexpr int T_ = 2048, E_ = 1024, H_ = 16, D_ = 64;

DEVI unsigned short f2b(float f) {
  union { float fv; unsigned u; } c; c.fv = f;
  unsigned r = c.u + 0x7fffu + ((c.u >> 16) & 1u);
  return (unsigned short)(r >> 16);
}

DEVI f32x4 mfma16(bf16x8 a, bf16x8 b, f32x4 c) {
  return __builtin_amdgcn_mfma_f32_16x16x32_bf16(a, b, c, 0, 0, 0);
}

// ---------------- QKV projection (round-1 verbatim, known good) ----------------
// grid: (B*H=32, T/256=8), block 256
__launch_bounds__(256)
__global__ void qkv_kernel(const float* __restrict__ x,
                           const float* __restrict__ Wq, const float* __restrict__ bq,
                           const float* __restrict__ Wk, const float* __restrict__ bk,
                           const float* __restrict__ Wv, const float* __restrict__ bv,
                           unsigned short* __restrict__ qo,
                           unsigned short* __restrict__ ko,
                           unsigned short* __restrict__ vto)
{
  const int bh = blockIdx.x;
  const int b  = bh >> 4;
  const int h  = bh & (H_ - 1);
  const int t0 = blockIdx.y * 256;
  __shared__ unsigned short Xl[256][72];
  __shared__ unsigned short Wl[3][64][72];
  const int tid = threadIdx.x;

  // stage X slice (256 x 64), f32 -> bf16
  #pragma unroll
  for (int p = 0; p < 16; ++p) {
    int idx = p * 256 + tid;
    int row = idx >> 4, c4 = idx & 15;
    const float* gp = x + ((size_t)(b * T_ + t0 + row)) * E_ + h * 64 + c4 * 4;
    float4 v = *(const float4*)gp;
    us4 o; o[0] = f2b(v.x); o[1] = f2b(v.y); o[2] = f2b(v.z); o[3] = f2b(v.w);
    *(us4*)&Xl[row][c4 * 4] = o;
  }
  // stage W blocks for this head (64 x 64 each); Wq pre-scaled by 1/8
  #pragma unroll
  for (int p = 0; p < 4; ++p) {
    int idx = p * 256 + tid;
    int row = idx >> 4, c4 = idx & 15;
    {
      float4 v = *(const float4*)(Wq + (size_t)(h * 64 + row) * 64 + c4 * 4);
      us4 o; o[0] = f2b(v.x * 0.125f); o[1] = f2b(v.y * 0.125f);
      o[2] = f2b(v.z * 0.125f); o[3] = f2b(v.w * 0.125f);
      *(us4*)&Wl[0][row][c4 * 4] = o;
    }
    {
      float4 v = *(const float4*)(Wk + (size_t)(h * 64 + row) * 64 + c4 * 4);
      us4 o; o[0] = f2b(v.x); o[1] = f2b(v.y); o[2] = f2b(v.z); o[3] = f2b(v.w);
      *(us4*)&Wl[1][row][c4 * 4] = o;
    }
    {
      float4 v = *(const float4*)(Wv + (size_t)(h * 64 + row) * 64 + c4 * 4);
      us4 o; o[0] = f2b(v.x); o[1] = f2b(v.y); o[2] = f2b(v.z); o[3] = f2b(v.w);
      *(us4*)&Wl[2][row][c4 * 4] = o;
    }
  }
  __syncthreads();

  const int w = tid >> 6, lane = tid & 63, lo = lane & 15, g = lane >> 4;
  const int tl0 = w * 64;

  // X B-fragments (used as B for Q/K transposed products)
  bf16x8 xb[4][2];
  #pragma unroll
  for (int tt = 0; tt < 4; ++tt)
    #pragma unroll
    for (int kd = 0; kd < 2; ++kd)
      xb[tt][kd] = *(const bf16x8*)&Xl[tl0 + tt * 16 + lo][kd * 32 + g * 8];

  // Q and K: C = W * X^T  (o x t); store row-major q[t][o] with packed 4-d stores
  #pragma unroll
  for (int tsel = 0; tsel < 2; ++tsel) {
    const float* bias = tsel ? bk : bq;
    unsigned short* outp = tsel ? ko : qo;
    const float bs = tsel ? 1.0f : 0.125f;
    #pragma unroll
    for (int ot = 0; ot < 4; ++ot) {
      bf16x8 a0 = *(const bf16x8*)&Wl[tsel][ot * 16 + lo][g * 8];
      bf16x8 a1 = *(const bf16x8*)&Wl[tsel][ot * 16 + lo][32 + g * 8];
      float4 bv4 = *(const float4*)(bias + h * 64 + ot * 16 + g * 4);
      float bb[4] = {bv4.x * bs, bv4.y * bs, bv4.z * bs, bv4.w * bs};
      #pragma unroll
      for (int tt = 0; tt < 4; ++tt) {
        f32x4 acc = {0.f, 0.f, 0.f, 0.f};
        acc = mfma16(a0, xb[tt][0], acc);
        acc = mfma16(a1, xb[tt][1], acc);
        int tg = t0 + tl0 + tt * 16 + lo;
        us4 pk;
        #pragma unroll
        for (int r = 0; r < 4; ++r) pk[r] = f2b(acc[r] + bb[r]);
        *(us4*)(outp + ((size_t)(bh * T_ + tg)) * 64 + ot * 16 + g * 4) = pk;
      }
    }
  }

  // V: C = X * W^T (t x o); store transposed vt[(bh*64+d)*T + t] packed over t
  #pragma unroll
  for (int rt = 0; rt < 4; ++rt) {
    bf16x8 a0 = *(const bf16x8*)&Xl[tl0 + rt * 16 + lo][g * 8];
    bf16x8 a1 = *(const bf16x8*)&Xl[tl0 + rt * 16 + lo][32 + g * 8];
    #pragma unroll
    for (int ct = 0; ct < 4; ++ct) {
      bf16x8 b0 = *(const bf16x8*)&Wl[2][ct * 16 + lo][g * 8];
      bf16x8 b1 = *(const bf16x8*)&Wl[2][ct * 16 + lo][32 + g * 8];
      f32x4 acc = {0.f, 0.f, 0.f, 0.f};
      acc = mfma16(a0, b0, acc);
      acc = mfma16(a1, b1, acc);
      int d = ct * 16 + lo;
      float bvs = bv[h * 64 + d];
      int tg = t0 + tl0 + rt * 16 + g * 4;
      us4 pk;
      #pragma unroll
      for (int r = 0; r < 4; ++r) pk[r] = f2b(acc[r] + bvs);
      *(us4*)(vto + ((size_t)(bh * 64 + d)) * T_ + tg) = pk;
    }
  }
}

// ---------------- causal flash attention ----------------
// grid: (B*H=32, T/128=16), block 256 (4 waves x 32 q-rows), double-buffered K/V
__launch_bounds__(256)
__global__ void flash_kernel(const unsigned short* __restrict__ q,
                             const unsigned short* __restrict__ kk_,
                             const unsigned short* __restrict__ vt,
                             unsigned short* __restrict__ ao)
{
  const int bh = blockIdx.x;
  const int qt = blockIdx.y;
  const int b = bh >> 4, h = bh & 15;
  const int t0 = qt * 128;
  __shared__ unsigned short Kl[2][64][72];
  __shared__ unsigned short Vl[2][64][72];
  __shared__ unsigned short Pl[4][32][72];
  const int tid = threadIdx.x, w = tid >> 6, lane = tid & 63, lo = lane & 15, g = lane >> 4;
  const int tw = t0 + w * 32;

  // staging addressing: each thread loads 2 K-us8 + 2 V-us8 per step
  const int srow = tid >> 3, sc8 = (tid & 7) * 8;
  const unsigned short* kbase = kk_ + ((size_t)bh * T_ + srow) * 64 + sc8;
  const unsigned short* vbase = vt + ((size_t)(bh * 64 + srow)) * T_ + sc8;

  // Q fragments (pre-scaled by 1/8 in qkv)
  bf16x8 qf[2][2];
  const unsigned short* qb = q + ((size_t)(bh * T_ + tw)) * 64;
  #pragma unroll
  for (int tt = 0; tt < 2; ++tt)
    #pragma unroll
    for (int kd = 0; kd < 2; ++kd)
      qf[tt][kd] = *(const bf16x8*)(qb + (size_t)(tt * 16 + lo) * 64 + kd * 32 + g * 8);

  float m_[2] = {-1e30f, -1e30f};
  float l_[2] = {0.f, 0.f};
  f32x4 zero4 = {0.f, 0.f, 0.f, 0.f};
  f32x4 oacc[4][2];
  #pragma unroll
  for (int dt = 0; dt < 4; ++dt)
    #pragma unroll
    for (int tt = 0; tt < 2; ++tt) oacc[dt][tt] = zero4;

  // prologue: stage step 0 into buffer 0
  us8 kr0 = *(const us8*)(kbase);
  us8 kr1 = *(const us8*)(kbase + 32 * 64);
  us8 vr0 = *(const us8*)(vbase);
  us8 vr1 = *(const us8*)(vbase + (size_t)32 * T_);
  *(us8*)&Kl[0][srow][sc8] = kr0;
  *(us8*)&Kl[0][srow + 32][sc8] = kr1;
  *(us8*)&Vl[0][srow][sc8] = vr0;
  *(us8*)&Vl[0][srow + 32][sc8] = vr1;
  __syncthreads();

  const int nsteps = (t0 + 128) >> 6;
  for (int stp = 0; stp < nsteps; ++stp) {
    const int s0 = stp * 64;
    const int cur = stp & 1;
    // prefetch next step into registers (overlaps with compute below)
    if (stp + 1 < nsteps) {
      const int sn = s0 + 64;
      kr0 = *(const us8*)(kbase + (size_t)sn * 64);
      kr1 = *(const us8*)(kbase + (size_t)(sn + 32) * 64);
      vr0 = *(const us8*)(vbase + sn);
      vr1 = *(const us8*)(vbase + sn + (size_t)32 * T_);
    }
    if (s0 <= tw + 31) {
      // S^T = K * Q^T : col = t (lane&15), row = s
      f32x4 sacc[4][2];
      #pragma unroll
      for (int ss = 0; ss < 4; ++ss)
        #pragma unroll
        for (int tt = 0; tt < 2; ++tt) sacc[ss][tt] = zero4;
      #pragma unroll
      for (int ss = 0; ss < 4; ++ss) {
        bf16x8 ka0 = *(const bf16x8*)&Kl[cur][ss * 16 + lo][g * 8];
        bf16x8 ka1 = *(const bf16x8*)&Kl[cur][ss * 16 + lo][32 + g * 8];
        #pragma unroll
        for (int tt = 0; tt < 2; ++tt) {
          sacc[ss][tt] = mfma16(ka0, qf[tt][0], sacc[ss][tt]);
          sacc[ss][tt] = mfma16(ka1, qf[tt][1], sacc[ss][tt]);
        }
      }
      if (s0 + 63 > tw) {  // diagonal step: causal mask
        #pragma unroll
        for (int ss = 0; ss < 4; ++ss)
          #pragma unroll
          for (int tt = 0; tt < 2; ++tt)
            #pragma unroll
            for (int r = 0; r < 4; ++r) {
              int sg = s0 + ss * 16 + g * 4 + r;
              int tg = tw + tt * 16 + lo;
              if (sg > tg) sacc[ss][tt][r] = -1e30f;
            }
      }
      // online softmax over s (per lane column t)
      #pragma unroll
      for (int tt = 0; tt < 2; ++tt) {
        float mx = -1e30f;
        #pragma unroll
        for (int ss = 0; ss < 4; ++ss)
          #pragma unroll
          for (int r = 0; r < 4; ++r) mx = fmaxf(mx, sacc[ss][tt][r]);
        mx = fmaxf(mx, __shfl_xor(mx, 16));
        mx = fmaxf(mx, __shfl_xor(mx, 32));
        float mn = fmaxf(m_[tt], mx);
        float corr = __expf(m_[tt] - mn);
        m_[tt] = mn;
        float sum = 0.f;
        #pragma unroll
        for (int ss = 0; ss < 4; ++ss) {
          us4 pk;
          #pragma unroll
          for (int r = 0; r < 4; ++r) {
            float pv = __expf(sacc[ss][tt][r] - mn);
            sum += pv;
            pk[r] = f2b(pv);
          }
          *(us4*)&Pl[w][tt * 16 + lo][ss * 16 + g * 4] = pk;
        }
        sum += __shfl_xor(sum, 16);
        sum += __shfl_xor(sum, 32);
        l_[tt] = l_[tt] * corr + sum;
        #pragma unroll
        for (int dt = 0; dt < 4; ++dt) oacc[dt][tt] *= corr;
      }
      // O^T += Vt * P^T
      #pragma unroll
      for (int kh = 0; kh < 2; ++kh) {
        bf16x8 va[4];
        #pragma unroll
        for (int dt = 0; dt < 4; ++dt)
          va[dt] = *(const bf16x8*)&Vl[cur][dt * 16 + lo][kh * 32 + g * 8];
        #pragma unroll
        for (int tt = 0; tt < 2; ++tt) {
          bf16x8 pb = *(const bf16x8*)&Pl[w][tt * 16 + lo][kh * 32 + g * 8];
          #pragma unroll
          for (int dt = 0; dt < 4; ++dt)
            oacc[dt][tt] = mfma16(va[dt], pb, oacc[dt][tt]);
        }
      }
    }
    __syncthreads();
    if (stp + 1 < nsteps) {
      *(us8*)&Kl[cur ^ 1][srow][sc8] = kr0;
      *(us8*)&Kl[cur ^ 1][srow + 32][sc8] = kr1;
      *(us8*)&Vl[cur ^ 1][srow][sc8] = vr0;
      *(us8*)&Vl[cur ^ 1][srow + 32][sc8] = vr1;
      __syncthreads();
    }
  }
  // epilogue
  #pragma unroll
  for (int tt = 0; tt < 2; ++tt) {
    float inv = 1.0f / l_[tt];
    int tg = tw + tt * 16 + lo;
    unsigned short* op = ao + ((size_t)(b * T_ + tg)) * E_ + h * 64;
    #pragma unroll
    for (int dt = 0; dt < 4; ++dt) {
      us4 pk;
      #pragma unroll
      for (int r = 0; r < 4; ++r) pk[r] = f2b(oacc[dt][tt][r] * inv);
      *(us4*)(op + dt * 16 + g * 4) = pk;
    }
  }
}

// ---------------- output projection (round-1 verbatim, known good) ----------------
// grid: (4096/128=32, 1024/128=8), block 256 (2x2 waves of 64x64)
__launch_bounds__(256)
__global__ void proj_kernel(const unsigned short* __restrict__ ao,
                            const float* __restrict__ wp,
                            const float* __restrict__ bp,
                            float* __restrict__ out)
{
  const int m0 = blockIdx.x * 128;
  const int n0 = blockIdx.y * 128;
  __shared__ unsigned short Al[128][40];
  __shared__ unsigned short Bl[128][40];
  const int tid = threadIdx.x, w = tid >> 6, lane = tid & 63, lo = lane & 15, g = lane >> 4;
  const int wr = (w >> 1) * 64, wc = (w & 1) * 64;
  f32x4 zero4 = {0.f, 0.f, 0.f, 0.f};
  f32x4 acc[4][4];
  #pragma unroll
  for (int i = 0; i < 4; ++i)
    #pragma unroll
    for (int j = 0; j < 4; ++j) acc[i][j] = zero4;

  for (int k0 = 0; k0 < 1024; k0 += 32) {
    __syncthreads();
    #pragma unroll
    for (int p = 0; p < 2; ++p) {
      int ii = p * 256 + tid;
      int row = ii >> 2, c = ii & 3;
      *(us8*)&Al[row][c * 8] = *(const us8*)(ao + (size_t)(m0 + row) * 1024 + k0 + c * 8);
    }
    #pragma unroll
    for (int p = 0; p < 4; ++p) {
      int ii = p * 256 + tid;
      int row = ii >> 3, c4 = ii & 7;
      float4 v = *(const float4*)(wp + (size_t)(n0 + row) * 1024 + k0 + c4 * 4);
      us4 o; o[0] = f2b(v.x); o[1] = f2b(v.y); o[2] = f2b(v.z); o[3] = f2b(v.w);
      *(us4*)&Bl[row][c4 * 4] = o;
    }
    __syncthreads();
    bf16x8 af[4], bfr[4];
    #pragma unroll
    for (int i = 0; i < 4; ++i) af[i] = *(const bf16x8*)&Al[wr + i * 16 + lo][g * 8];
    #pragma unroll
    for (int j = 0; j < 4; ++j) bfr[j] = *(const bf16x8*)&Bl[wc + j * 16 + lo][g * 8];
    #pragma unroll
    for (int i = 0; i < 4; ++i)
      #pragma unroll
      for (int j = 0; j < 4; ++j)
        acc[i][j] = mfma16(af[i], bfr[j], acc[i][j]);
  }
  #pragma unroll
  for (int j = 0; j < 4; ++j) {
    int n = n0 + wc + j * 16 + lo;
    float bias = bp[n];
    #pragma unroll
    for (int i = 0; i < 4; ++i) {
      #pragma unroll
      for (int r = 0; r < 4; ++r)
        out[(size_t)(m0 + wr + i * 16 + g * 4 + r) * 1024 + n] = acc[i][j][r] + bias;
    }
  }
}

extern "C" void kernel_launch(void* const* d_in, const int* in_sizes, int n_in,
                              void* d_out, int out_size, void* d_ws, size_t ws_size,
                              hipStream_t stream)
{
  const float* x  = (const float*)d_in[0];
  const float* Wq = (const float*)d_in[2];
  const float* bq = (const float*)d_in[3];
  const float* Wk = (const float*)d_in[4];
  const float* bk = (const float*)d_in[5];
  const float* Wv = (const float*)d_in[6];
  const float* bv = (const float*)d_in[7];
  const float* Wp = (const float*)d_in[8];
  const float* bp = (const float*)d_in[9];
  float* out = (float*)d_out;

  char* ws = (char*)d_ws;
  const size_t SZ = (size_t)2 * 16 * 2048 * 64 * 2;  // 8 MB per bf16 tensor
  unsigned short* q  = (unsigned short*)(ws);
  unsigned short* kb = (unsigned short*)(ws + SZ);
  unsigned short* vt = (unsigned short*)(ws + 2 * SZ);
  unsigned short* ao = (unsigned short*)(ws + 3 * SZ);

  qkv_kernel<<<dim3(32, 8), 256, 0, stream>>>(x, Wq, bq, Wk, bk, Wv, bv, q, kb, vt);
  flash_kernel<<<dim3(32, 16), 256, 0, stream>>>(q, kb, vt, ao);
  proj_kernel<<<dim3(32, 8), 256, 0, stream>>>(ao, Wp, bp, out);
}

// Round 4
// 100.438 us; speedup vs baseline: 1.4440x; 1.2238x over previous
//
#include <hip/hip_runtime.h>

typedef __attribute__((ext_vector_type(4))) float f32x4;
typedef __attribute__((ext_vector_type(8))) __bf16 bf16x8;
typedef __attribute__((ext_vector_type(4))) unsigned short us4;
typedef __attribute__((ext_vector_type(8))) unsigned short us8;

#define DEVI static __device__ __forceinline__

constexpr int T_ = 2048, E_ = 1024, H_ = 16, D_ = 64;

DEVI unsigned short f2b(float f) {
  union { float fv; unsigned u; } c; c.fv = f;
  unsigned r = c.u + 0x7fffu + ((c.u >> 16) & 1u);
  return (unsigned short)(r >> 16);
}

DEVI f32x4 mfma16(bf16x8 a, bf16x8 b, f32x4 c) {
  return __builtin_amdgcn_mfma_f32_16x16x32_bf16(a, b, c, 0, 0, 0);
}

// ---------------- QKV projection ----------------
// grid: (B*H=32, T/128=16), block 256 (4 waves x 32 rows)
__launch_bounds__(256)
__global__ void qkv_kernel(const float* __restrict__ x,
                           const float* __restrict__ Wq, const float* __restrict__ bq,
                           const float* __restrict__ Wk, const float* __restrict__ bk,
                           const float* __restrict__ Wv, const float* __restrict__ bv,
                           unsigned short* __restrict__ qo,
                           unsigned short* __restrict__ ko,
                           unsigned short* __restrict__ vto)
{
  const int bh = blockIdx.x;
  const int b  = bh >> 4;
  const int h  = bh & (H_ - 1);
  const int t0 = blockIdx.y * 128;
  __shared__ unsigned short Xl[128][72];
  __shared__ unsigned short Wl[3][64][72];
  const int tid = threadIdx.x;

  // stage X slice (128 x 64), f32 -> bf16
  #pragma unroll
  for (int p = 0; p < 8; ++p) {
    int idx = p * 256 + tid;
    int row = idx >> 4, c4 = idx & 15;
    const float* gp = x + ((size_t)(b * T_ + t0 + row)) * E_ + h * 64 + c4 * 4;
    float4 v = *(const float4*)gp;
    us4 o; o[0] = f2b(v.x); o[1] = f2b(v.y); o[2] = f2b(v.z); o[3] = f2b(v.w);
    *(us4*)&Xl[row][c4 * 4] = o;
  }
  // stage W blocks for this head (64 x 64 each); Wq pre-scaled by 1/8
  #pragma unroll
  for (int p = 0; p < 4; ++p) {
    int idx = p * 256 + tid;
    int row = idx >> 4, c4 = idx & 15;
    {
      float4 v = *(const float4*)(Wq + (size_t)(h * 64 + row) * 64 + c4 * 4);
      us4 o; o[0] = f2b(v.x * 0.125f); o[1] = f2b(v.y * 0.125f);
      o[2] = f2b(v.z * 0.125f); o[3] = f2b(v.w * 0.125f);
      *(us4*)&Wl[0][row][c4 * 4] = o;
    }
    {
      float4 v = *(const float4*)(Wk + (size_t)(h * 64 + row) * 64 + c4 * 4);
      us4 o; o[0] = f2b(v.x); o[1] = f2b(v.y); o[2] = f2b(v.z); o[3] = f2b(v.w);
      *(us4*)&Wl[1][row][c4 * 4] = o;
    }
    {
      float4 v = *(const float4*)(Wv + (size_t)(h * 64 + row) * 64 + c4 * 4);
      us4 o; o[0] = f2b(v.x); o[1] = f2b(v.y); o[2] = f2b(v.z); o[3] = f2b(v.w);
      *(us4*)&Wl[2][row][c4 * 4] = o;
    }
  }
  __syncthreads();

  const int w = tid >> 6, lane = tid & 63, lo = lane & 15, g = lane >> 4;
  const int tl0 = w * 32;

  // X B-fragments
  bf16x8 xb[2][2];
  #pragma unroll
  for (int tt = 0; tt < 2; ++tt)
    #pragma unroll
    for (int kd = 0; kd < 2; ++kd)
      xb[tt][kd] = *(const bf16x8*)&Xl[tl0 + tt * 16 + lo][kd * 32 + g * 8];

  // Q and K: C = W * X^T  (o x t); store row-major q[t][o]
  #pragma unroll
  for (int tsel = 0; tsel < 2; ++tsel) {
    const float* bias = tsel ? bk : bq;
    unsigned short* outp = tsel ? ko : qo;
    const float bs = tsel ? 1.0f : 0.125f;
    #pragma unroll
    for (int ot = 0; ot < 4; ++ot) {
      bf16x8 a0 = *(const bf16x8*)&Wl[tsel][ot * 16 + lo][g * 8];
      bf16x8 a1 = *(const bf16x8*)&Wl[tsel][ot * 16 + lo][32 + g * 8];
      float4 bv4 = *(const float4*)(bias + h * 64 + ot * 16 + g * 4);
      float bb[4] = {bv4.x * bs, bv4.y * bs, bv4.z * bs, bv4.w * bs};
      #pragma unroll
      for (int tt = 0; tt < 2; ++tt) {
        f32x4 acc = {0.f, 0.f, 0.f, 0.f};
        acc = mfma16(a0, xb[tt][0], acc);
        acc = mfma16(a1, xb[tt][1], acc);
        int tg = t0 + tl0 + tt * 16 + lo;
        us4 pk;
        #pragma unroll
        for (int r = 0; r < 4; ++r) pk[r] = f2b(acc[r] + bb[r]);
        *(us4*)(outp + ((size_t)(bh * T_ + tg)) * 64 + ot * 16 + g * 4) = pk;
      }
    }
  }

  // V: C = X * W^T (t x o); store transposed vt[(bh*64+d)*T + t]
  #pragma unroll
  for (int rt = 0; rt < 2; ++rt) {
    bf16x8 a0 = *(const bf16x8*)&Xl[tl0 + rt * 16 + lo][g * 8];
    bf16x8 a1 = *(const bf16x8*)&Xl[tl0 + rt * 16 + lo][32 + g * 8];
    #pragma unroll
    for (int ct = 0; ct < 4; ++ct) {
      bf16x8 b0 = *(const bf16x8*)&Wl[2][ct * 16 + lo][g * 8];
      bf16x8 b1 = *(const bf16x8*)&Wl[2][ct * 16 + lo][32 + g * 8];
      f32x4 acc = {0.f, 0.f, 0.f, 0.f};
      acc = mfma16(a0, b0, acc);
      acc = mfma16(a1, b1, acc);
      int d = ct * 16 + lo;
      float bvs = bv[h * 64 + d];
      int tg = t0 + tl0 + rt * 16 + g * 4;
      us4 pk;
      #pragma unroll
      for (int r = 0; r < 4; ++r) pk[r] = f2b(acc[r] + bvs);
      *(us4*)(vto + ((size_t)(bh * 64 + d)) * T_ + tg) = pk;
    }
  }
}

// ---------------- causal flash attention ----------------
// grid: (B*H=32, 8), block 512 = 8 waves x 16 q-rows.
// Block y processes q-tiles y and 15-y sequentially -> 34 KV steps per block
// (perfect balance). LDS tiles are linear [64][64] shorts with 16B-granule
// XOR swizzle (granule ^= row&7) to kill ds_read_b128 bank conflicts (m214).
__launch_bounds__(512)
__global__ void flash_kernel(const unsigned short* __restrict__ q,
                             const unsigned short* __restrict__ kk_,
                             const unsigned short* __restrict__ vt,
                             unsigned short* __restrict__ ao)
{
  const int bh = blockIdx.x;
  const int b = bh >> 4, h = bh & 15;
  __shared__ unsigned short Kl[2][64][64];
  __shared__ unsigned short Vl[2][64][64];
  __shared__ unsigned short Pl[8][16][64];
  const int tid = threadIdx.x, w = tid >> 6, lane = tid & 63, lo = lane & 15, g = lane >> 4;
  const int rs = lo & 7;  // read-side swizzle key (row & 7 == lo & 7 for all our rows)

  // staging: 512 threads x us8 = exactly one 64x64 tile each for K and V
  const int srow = tid >> 3, sgi = tid & 7;
  const int sgis = (sgi ^ (srow & 7)) * 8;  // swizzled short-col for writes
  const unsigned short* kbase = kk_ + ((size_t)bh * T_ + srow) * 64 + sgi * 8;
  const unsigned short* vbase = vt + ((size_t)(bh * 64 + srow)) * T_ + sgi * 8;

  #pragma unroll 1
  for (int half = 0; half < 2; ++half) {
    const int qt = half ? (15 - blockIdx.y) : blockIdx.y;
    const int t0 = qt * 128;
    const int tw = t0 + w * 16;  // this wave's 16 q-rows start

    // Q fragments (pre-scaled by 1/8 in qkv): per lane row t = tw + lo
    bf16x8 qf[2];
    const unsigned short* qb = q + ((size_t)(bh * T_ + tw + lo)) * 64;
    #pragma unroll
    for (int kd = 0; kd < 2; ++kd)
      qf[kd] = *(const bf16x8*)(qb + kd * 32 + g * 8);

    float m_ = -1e30f, l_ = 0.f;
    f32x4 zero4 = {0.f, 0.f, 0.f, 0.f};
    f32x4 oacc[4];
    #pragma unroll
    for (int dt = 0; dt < 4; ++dt) oacc[dt] = zero4;

    // prologue: stage step 0 into buffer 0
    us8 kr = *(const us8*)(kbase);
    us8 vr = *(const us8*)(vbase);
    __syncthreads();  // protect any prior use of buffer 0
    *(us8*)&Kl[0][srow][sgis] = kr;
    *(us8*)&Vl[0][srow][sgis] = vr;
    __syncthreads();

    const int nsteps = (t0 + 128) >> 6;
    for (int stp = 0; stp < nsteps; ++stp) {
      const int s0 = stp * 64;
      const int cur = stp & 1;
      if (stp + 1 < nsteps) {  // register prefetch of next K/V tile
        kr = *(const us8*)(kbase + (size_t)(s0 + 64) * 64);
        vr = *(const us8*)(vbase + s0 + 64);
      }
      if (s0 <= tw + 15) {
        // S^T = K * Q^T : col = t (lo), rows s = s0 + ss*16 + g*4 + r
        f32x4 sacc[4];
        #pragma unroll
        for (int ss = 0; ss < 4; ++ss) sacc[ss] = zero4;
        #pragma unroll
        for (int ss = 0; ss < 4; ++ss) {
          bf16x8 ka0 = *(const bf16x8*)&Kl[cur][ss * 16 + lo][(g ^ rs) * 8];
          bf16x8 ka1 = *(const bf16x8*)&Kl[cur][ss * 16 + lo][((g | 4) ^ rs) * 8];
          sacc[ss] = mfma16(ka0, qf[0], sacc[ss]);
          sacc[ss] = mfma16(ka1, qf[1], sacc[ss]);
        }
        if (s0 + 63 > tw) {  // diagonal step: causal mask
          #pragma unroll
          for (int ss = 0; ss < 4; ++ss)
            #pragma unroll
            for (int r = 0; r < 4; ++r) {
              int sg = s0 + ss * 16 + g * 4 + r;
              if (sg > tw + lo) sacc[ss][r] = -1e30f;
            }
        }
        // online softmax over s for column t = tw + lo (spread over g-groups)
        float mx = -1e30f;
        #pragma unroll
        for (int ss = 0; ss < 4; ++ss)
          #pragma unroll
          for (int r = 0; r < 4; ++r) mx = fmaxf(mx, sacc[ss][r]);
        mx = fmaxf(mx, __shfl_xor(mx, 16));
        mx = fmaxf(mx, __shfl_xor(mx, 32));
        float mn = fmaxf(m_, mx);
        float corr = __expf(m_ - mn);
        m_ = mn;
        float sum = 0.f;
        #pragma unroll
        for (int ss = 0; ss < 4; ++ss) {
          us4 pk;
          #pragma unroll
          for (int r = 0; r < 4; ++r) {
            float pv = __expf(sacc[ss][r] - mn);
            sum += pv;
            pk[r] = f2b(pv);
          }
          // logical Pl[w][lo][ss*16 + g*4]; granule = ss*2 + (g>>1), offset (g&1)*4
          *(us4*)&Pl[w][lo][(((ss * 2 + (g >> 1)) ^ rs) << 3) + (g & 1) * 4] = pk;
        }
        sum += __shfl_xor(sum, 16);
        sum += __shfl_xor(sum, 32);
        l_ = l_ * corr + sum;
        #pragma unroll
        for (int dt = 0; dt < 4; ++dt) oacc[dt] *= corr;
        // O^T += Vt * P^T
        #pragma unroll
        for (int kh = 0; kh < 2; ++kh) {
          bf16x8 pb = *(const bf16x8*)&Pl[w][lo][((kh * 4 + g) ^ rs) * 8];
          #pragma unroll
          for (int dt = 0; dt < 4; ++dt) {
            bf16x8 va = *(const bf16x8*)&Vl[cur][dt * 16 + lo][((kh * 4 + g) ^ rs) * 8];
            oacc[dt] = mfma16(va, pb, oacc[dt]);
          }
        }
      }
      __syncthreads();
      if (stp + 1 < nsteps) {
        *(us8*)&Kl[cur ^ 1][srow][sgis] = kr;
        *(us8*)&Vl[cur ^ 1][srow][sgis] = vr;
        __syncthreads();
      }
    }
    // epilogue: per lane row t = tw + lo, d = dt*16 + g*4 + r
    float inv = 1.0f / l_;
    unsigned short* op = ao + ((size_t)(b * T_ + tw + lo)) * E_ + h * 64;
    #pragma unroll
    for (int dt = 0; dt < 4; ++dt) {
      us4 pk;
      #pragma unroll
      for (int r = 0; r < 4; ++r) pk[r] = f2b(oacc[dt][r] * inv);
      *(us4*)(op + dt * 16 + g * 4) = pk;
    }
  }
}

// ---------------- output projection (round-1 verbatim, known good) ----------------
// grid: (4096/128=32, 1024/128=8), block 256 (2x2 waves of 64x64)
__launch_bounds__(256)
__global__ void proj_kernel(const unsigned short* __restrict__ ao,
                            const float* __restrict__ wp,
                            const float* __restrict__ bp,
                            float* __restrict__ out)
{
  const int m0 = blockIdx.x * 128;
  const int n0 = blockIdx.y * 128;
  __shared__ unsigned short Al[128][40];
  __shared__ unsigned short Bl[128][40];
  const int tid = threadIdx.x, w = tid >> 6, lane = tid & 63, lo = lane & 15, g = lane >> 4;
  const int wr = (w >> 1) * 64, wc = (w & 1) * 64;
  f32x4 zero4 = {0.f, 0.f, 0.f, 0.f};
  f32x4 acc[4][4];
  #pragma unroll
  for (int i = 0; i < 4; ++i)
    #pragma unroll
    for (int j = 0; j < 4; ++j) acc[i][j] = zero4;

  for (int k0 = 0; k0 < 1024; k0 += 32) {
    __syncthreads();
    #pragma unroll
    for (int p = 0; p < 2; ++p) {
      int ii = p * 256 + tid;
      int row = ii >> 2, c = ii & 3;
      *(us8*)&Al[row][c * 8] = *(const us8*)(ao + (size_t)(m0 + row) * 1024 + k0 + c * 8);
    }
    #pragma unroll
    for (int p = 0; p < 4; ++p) {
      int ii = p * 256 + tid;
      int row = ii >> 3, c4 = ii & 7;
      float4 v = *(const float4*)(wp + (size_t)(n0 + row) * 1024 + k0 + c4 * 4);
      us4 o; o[0] = f2b(v.x); o[1] = f2b(v.y); o[2] = f2b(v.z); o[3] = f2b(v.w);
      *(us4*)&Bl[row][c4 * 4] = o;
    }
    __syncthreads();
    bf16x8 af[4], bfr[4];
    #pragma unroll
    for (int i = 0; i < 4; ++i) af[i] = *(const bf16x8*)&Al[wr + i * 16 + lo][g * 8];
    #pragma unroll
    for (int j = 0; j < 4; ++j) bfr[j] = *(const bf16x8*)&Bl[wc + j * 16 + lo][g * 8];
    #pragma unroll
    for (int i = 0; i < 4; ++i)
      #pragma unroll
      for (int j = 0; j < 4; ++j)
        acc[i][j] = mfma16(af[i], bfr[j], acc[i][j]);
  }
  #pragma unroll
  for (int j = 0; j < 4; ++j) {
    int n = n0 + wc + j * 16 + lo;
    float bias = bp[n];
    #pragma unroll
    for (int i = 0; i < 4; ++i) {
      #pragma unroll
      for (int r = 0; r < 4; ++r)
        out[(size_t)(m0 + wr + i * 16 + g * 4 + r) * 1024 + n] = acc[i][j][r] + bias;
    }
  }
}

extern "C" void kernel_launch(void* const* d_in, const int* in_sizes, int n_in,
                              void* d_out, int out_size, void* d_ws, size_t ws_size,
                              hipStream_t stream)
{
  const float* x  = (const float*)d_in[0];
  const float* Wq = (const float*)d_in[2];
  const float* bq = (const float*)d_in[3];
  const float* Wk = (const float*)d_in[4];
  const float* bk = (const float*)d_in[5];
  const float* Wv = (const float*)d_in[6];
  const float* bv = (const float*)d_in[7];
  const float* Wp = (const float*)d_in[8];
  const float* bp = (const float*)d_in[9];
  float* out = (float*)d_out;

  char* ws = (char*)d_ws;
  const size_t SZ = (size_t)2 * 16 * 2048 * 64 * 2;  // 8 MB per bf16 tensor
  unsigned short* q  = (unsigned short*)(ws);
  unsigned short* kb = (unsigned short*)(ws + SZ);
  unsigned short* vt = (unsigned short*)(ws + 2 * SZ);
  unsigned short* ao = (unsigned short*)(ws + 3 * SZ);

  qkv_kernel<<<dim3(32, 16), 256, 0, stream>>>(x, Wq, bq, Wk, bk, Wv, bv, q, kb, vt);
  flash_kernel<<<dim3(32, 8), 512, 0, stream>>>(q, kb, vt, ao);
  proj_kernel<<<dim3(32, 8), 256, 0, stream>>>(ao, Wp, bp, out);
}

// Round 5
// 89.052 us; speedup vs baseline: 1.6287x; 1.1279x over previous
//
#include <hip/hip_runtime.h>

typedef __attribute__((ext_vector_type(4))) float f32x4;
typedef __attribute__((ext_vector_type(8))) __bf16 bf16x8;
typedef __attribute__((ext_vector_type(4))) unsigned short us4;
typedef __attribute__((ext_vector_type(8))) unsigned short us8;

#define DEVI static __device__ __forceinline__

constexpr int T_ = 2048, E_ = 1024, H_ = 16, D_ = 64;
#define QSCALE (0.125f * 1.44269504088896f)  /* 1/sqrt(D) * log2(e) */

DEVI unsigned short f2b(float f) {
  union { float fv; unsigned u; } c; c.fv = f;
  unsigned r = c.u + 0x7fffu + ((c.u >> 16) & 1u);
  return (unsigned short)(r >> 16);
}

#if __has_builtin(__builtin_amdgcn_exp2f)
DEVI float fexp2(float x) { return __builtin_amdgcn_exp2f(x); }
#else
DEVI float fexp2(float x) { return __expf(x * 0.69314718056f); }
#endif

DEVI f32x4 mfma16(bf16x8 a, bf16x8 b, f32x4 c) {
  return __builtin_amdgcn_mfma_f32_16x16x32_bf16(a, b, c, 0, 0, 0);
}

// ---------------- weight conversion kernels (run once) ----------------
// grid 192: blocks [0,64)=Wq (scaled), [64,128)=Wk, [128,192)=Wv
__launch_bounds__(256)
__global__ void wcvt_kernel(const float* __restrict__ Wq,
                            const float* __restrict__ Wk,
                            const float* __restrict__ Wv,
                            unsigned short* __restrict__ wqb,
                            unsigned short* __restrict__ wkb,
                            unsigned short* __restrict__ wvb)
{
  int blk = blockIdx.x;
  const float* src; unsigned short* dst; float s = 1.0f;
  if (blk < 64)       { src = Wq; dst = wqb; s = QSCALE; }
  else if (blk < 128) { src = Wk; dst = wkb; blk -= 64; }
  else                { src = Wv; dst = wvb; blk -= 128; }
  int i = blk * 256 + threadIdx.x;  // [0,16384) float4s
  float4 v = *(const float4*)(src + (size_t)i * 4);
  us4 o; o[0] = f2b(v.x * s); o[1] = f2b(v.y * s); o[2] = f2b(v.z * s); o[3] = f2b(v.w * s);
  *(us4*)(dst + (size_t)i * 4) = o;
}

// grid 1024: Wp (1024x1024 f32) -> bf16
__launch_bounds__(256)
__global__ void wpcvt_kernel(const float* __restrict__ Wp,
                             unsigned short* __restrict__ wpb)
{
  int i = blockIdx.x * 256 + threadIdx.x;  // [0,262144) float4s
  float4 v = *(const float4*)(Wp + (size_t)i * 4);
  us4 o; o[0] = f2b(v.x); o[1] = f2b(v.y); o[2] = f2b(v.z); o[3] = f2b(v.w);
  *(us4*)(wpb + (size_t)i * 4) = o;
}

// ---------------- QKV projection ----------------
// grid: (B*H=32, T/128=16), block 256 (4 waves x 32 rows); bf16 weights
__launch_bounds__(256)
__global__ void qkv_kernel(const float* __restrict__ x,
                           const unsigned short* __restrict__ wqb,
                           const float* __restrict__ bq,
                           const unsigned short* __restrict__ wkb,
                           const float* __restrict__ bk,
                           const unsigned short* __restrict__ wvb,
                           const float* __restrict__ bv,
                           unsigned short* __restrict__ qo,
                           unsigned short* __restrict__ ko,
                           unsigned short* __restrict__ vto)
{
  const int bh = blockIdx.x;
  const int b  = bh >> 4;
  const int h  = bh & (H_ - 1);
  const int t0 = blockIdx.y * 128;
  __shared__ unsigned short Xl[128][72];
  __shared__ unsigned short Wl[3][64][72];
  const int tid = threadIdx.x;

  // stage X slice (128 x 64), f32 -> bf16
  #pragma unroll
  for (int p = 0; p < 8; ++p) {
    int idx = p * 256 + tid;
    int row = idx >> 4, c4 = idx & 15;
    const float* gp = x + ((size_t)(b * T_ + t0 + row)) * E_ + h * 64 + c4 * 4;
    float4 v = *(const float4*)gp;
    us4 o; o[0] = f2b(v.x); o[1] = f2b(v.y); o[2] = f2b(v.z); o[3] = f2b(v.w);
    *(us4*)&Xl[row][c4 * 4] = o;
  }
  // stage pre-converted bf16 W blocks for this head (64x64 each)
  {
    const unsigned short* wsrc0 = wqb + (size_t)h * 4096;
    const unsigned short* wsrc1 = wkb + (size_t)h * 4096;
    const unsigned short* wsrc2 = wvb + (size_t)h * 4096;
    #pragma unroll
    for (int p = 0; p < 2; ++p) {
      int idx = p * 256 + tid;
      int row = idx >> 3, c8 = (idx & 7) * 8;
      *(us8*)&Wl[0][row][c8] = *(const us8*)(wsrc0 + row * 64 + c8);
      *(us8*)&Wl[1][row][c8] = *(const us8*)(wsrc1 + row * 64 + c8);
      *(us8*)&Wl[2][row][c8] = *(const us8*)(wsrc2 + row * 64 + c8);
    }
  }
  __syncthreads();

  const int w = tid >> 6, lane = tid & 63, lo = lane & 15, g = lane >> 4;
  const int tl0 = w * 32;

  // X B-fragments
  bf16x8 xb[2][2];
  #pragma unroll
  for (int tt = 0; tt < 2; ++tt)
    #pragma unroll
    for (int kd = 0; kd < 2; ++kd)
      xb[tt][kd] = *(const bf16x8*)&Xl[tl0 + tt * 16 + lo][kd * 32 + g * 8];

  // Q and K: C = W * X^T  (o x t); store row-major q[t][o]
  #pragma unroll
  for (int tsel = 0; tsel < 2; ++tsel) {
    const float* bias = tsel ? bk : bq;
    unsigned short* outp = tsel ? ko : qo;
    const float bs = tsel ? 1.0f : QSCALE;
    #pragma unroll
    for (int ot = 0; ot < 4; ++ot) {
      bf16x8 a0 = *(const bf16x8*)&Wl[tsel][ot * 16 + lo][g * 8];
      bf16x8 a1 = *(const bf16x8*)&Wl[tsel][ot * 16 + lo][32 + g * 8];
      float4 bv4 = *(const float4*)(bias + h * 64 + ot * 16 + g * 4);
      float bb[4] = {bv4.x * bs, bv4.y * bs, bv4.z * bs, bv4.w * bs};
      #pragma unroll
      for (int tt = 0; tt < 2; ++tt) {
        f32x4 acc = {0.f, 0.f, 0.f, 0.f};
        acc = mfma16(a0, xb[tt][0], acc);
        acc = mfma16(a1, xb[tt][1], acc);
        int tg = t0 + tl0 + tt * 16 + lo;
        us4 pk;
        #pragma unroll
        for (int r = 0; r < 4; ++r) pk[r] = f2b(acc[r] + bb[r]);
        *(us4*)(outp + ((size_t)(bh * T_ + tg)) * 64 + ot * 16 + g * 4) = pk;
      }
    }
  }

  // V: C = X * W^T (t x o); store transposed vt[(bh*64+d)*T + t]
  #pragma unroll
  for (int rt = 0; rt < 2; ++rt) {
    bf16x8 a0 = *(const bf16x8*)&Xl[tl0 + rt * 16 + lo][g * 8];
    bf16x8 a1 = *(const bf16x8*)&Xl[tl0 + rt * 16 + lo][32 + g * 8];
    #pragma unroll
    for (int ct = 0; ct < 4; ++ct) {
      bf16x8 b0 = *(const bf16x8*)&Wl[2][ct * 16 + lo][g * 8];
      bf16x8 b1 = *(const bf16x8*)&Wl[2][ct * 16 + lo][32 + g * 8];
      f32x4 acc = {0.f, 0.f, 0.f, 0.f};
      acc = mfma16(a0, b0, acc);
      acc = mfma16(a1, b1, acc);
      int d = ct * 16 + lo;
      float bvs = bv[h * 64 + d];
      int tg = t0 + tl0 + rt * 16 + g * 4;
      us4 pk;
      #pragma unroll
      for (int r = 0; r < 4; ++r) pk[r] = f2b(acc[r] + bvs);
      *(us4*)(vto + ((size_t)(bh * 64 + d)) * T_ + tg) = pk;
    }
  }
}

// ---------------- causal flash attention ----------------
// grid: (B*H=32, 16), block 256 = 4 waves x 16 q-rows over a 64-row q-tile.
// Block y does q-tiles y and 31-y (33 steps, balanced). 2 LDS buffers,
// ONE barrier per step (write-next-after-compute), reg prefetch 2 ahead.
__launch_bounds__(256)
__global__ void flash_kernel(const unsigned short* __restrict__ q,
                             const unsigned short* __restrict__ kk_,
                             const unsigned short* __restrict__ vt,
                             unsigned short* __restrict__ ao)
{
  const int bh = blockIdx.x;
  const int b = bh >> 4, h = bh & 15;
  __shared__ unsigned short Kl[2][64][64];
  __shared__ unsigned short Vl[2][64][64];
  __shared__ unsigned short Pl[4][16][64];
  const int tid = threadIdx.x, w = tid >> 6, lane = tid & 63, lo = lane & 15, g = lane >> 4;
  const int rs = lo & 7;  // read-side swizzle key (row&7 == lo&7 for all rows we read)

  // staging: 256 threads, each 2 K-rows + 2 V-rows (us8 chunks), XOR-swizzled cols
  const int srow = tid >> 3, sgi = tid & 7;
  const int sgis = (sgi ^ (srow & 7)) * 8;  // (srow+32)&7 == srow&7, same key
  const unsigned short* kbase = kk_ + ((size_t)bh * T_ + srow) * 64 + sgi * 8;
  const unsigned short* vbase = vt + ((size_t)(bh * 64 + srow)) * T_ + sgi * 8;

  #pragma unroll 1
  for (int half = 0; half < 2; ++half) {
    const int qt = half ? (31 - blockIdx.y) : blockIdx.y;
    const int t0 = qt * 64;
    const int tw = t0 + w * 16;  // this wave's 16 q-rows start

    // Q fragments (pre-scaled by log2e/8): per-lane row t = tw + lo
    bf16x8 qf[2];
    const unsigned short* qb = q + ((size_t)(bh * T_ + tw + lo)) * 64;
    #pragma unroll
    for (int kd = 0; kd < 2; ++kd)
      qf[kd] = *(const bf16x8*)(qb + kd * 32 + g * 8);

    float m_ = -1e30f, l_ = 0.f;
    f32x4 zero4 = {0.f, 0.f, 0.f, 0.f};
    f32x4 oacc[4];
    #pragma unroll
    for (int dt = 0; dt < 4; ++dt) oacc[dt] = zero4;

    const int nsteps = qt + 1;
    // prologue: stage step 0; then load step-1 regs
    us8 kr0 = *(const us8*)(kbase);
    us8 kr1 = *(const us8*)(kbase + 2048);
    us8 vr0 = *(const us8*)(vbase);
    us8 vr1 = *(const us8*)(vbase + (size_t)32 * T_);
    *(us8*)&Kl[0][srow][sgis] = kr0;
    *(us8*)&Kl[0][srow + 32][sgis] = kr1;
    *(us8*)&Vl[0][srow][sgis] = vr0;
    *(us8*)&Vl[0][srow + 32][sgis] = vr1;
    if (nsteps > 1) {
      kr0 = *(const us8*)(kbase + 4096);
      kr1 = *(const us8*)(kbase + 4096 + 2048);
      vr0 = *(const us8*)(vbase + 64);
      vr1 = *(const us8*)(vbase + 64 + (size_t)32 * T_);
    }
    __syncthreads();

    for (int stp = 0; stp < nsteps; ++stp) {
      const int s0 = stp * 64;
      const int cur = stp & 1;
      us8 nk0, nk1, nv0, nv1;
      const bool pf = (stp + 2 < nsteps);
      if (pf) {  // issue loads for step stp+2 early
        const size_t ko_ = (size_t)(stp + 2) * 4096;
        nk0 = *(const us8*)(kbase + ko_);
        nk1 = *(const us8*)(kbase + ko_ + 2048);
        nv0 = *(const us8*)(vbase + (stp + 2) * 64);
        nv1 = *(const us8*)(vbase + (stp + 2) * 64 + (size_t)32 * T_);
      }
      {
        // S^T = K * Q^T : col = t (lo), rows s = s0 + ss*16 + g*4 + r
        f32x4 sacc[4];
        #pragma unroll
        for (int ss = 0; ss < 4; ++ss) sacc[ss] = zero4;
        __builtin_amdgcn_s_setprio(1);
        #pragma unroll
        for (int ss = 0; ss < 4; ++ss) {
          bf16x8 ka0 = *(const bf16x8*)&Kl[cur][ss * 16 + lo][(g ^ rs) * 8];
          bf16x8 ka1 = *(const bf16x8*)&Kl[cur][ss * 16 + lo][((g | 4) ^ rs) * 8];
          sacc[ss] = mfma16(ka0, qf[0], sacc[ss]);
          sacc[ss] = mfma16(ka1, qf[1], sacc[ss]);
        }
        __builtin_amdgcn_s_setprio(0);
        if (s0 + 63 > tw) {  // diagonal step: causal mask
          #pragma unroll
          for (int ss = 0; ss < 4; ++ss)
            #pragma unroll
            for (int r = 0; r < 4; ++r) {
              int sg = s0 + ss * 16 + g * 4 + r;
              if (sg > tw + lo) sacc[ss][r] = -1e30f;
            }
        }
        // online softmax (base 2) for column t = tw + lo
        float mx = -1e30f;
        #pragma unroll
        for (int ss = 0; ss < 4; ++ss)
          #pragma unroll
          for (int r = 0; r < 4; ++r) mx = fmaxf(mx, sacc[ss][r]);
        mx = fmaxf(mx, __shfl_xor(mx, 16));
        mx = fmaxf(mx, __shfl_xor(mx, 32));
        float mn = fmaxf(m_, mx);
        float corr = fexp2(m_ - mn);
        m_ = mn;
        float sum = 0.f;
        #pragma unroll
        for (int ss = 0; ss < 4; ++ss) {
          us4 pk;
          #pragma unroll
          for (int r = 0; r < 4; ++r) {
            float pv = fexp2(sacc[ss][r] - mn);
            sum += pv;
            pk[r] = f2b(pv);
          }
          // logical Pl[w][lo][ss*16 + g*4]; granule = ss*2+(g>>1), sub-off (g&1)*4
          *(us4*)&Pl[w][lo][(((ss * 2 + (g >> 1)) ^ rs) << 3) + (g & 1) * 4] = pk;
        }
        sum += __shfl_xor(sum, 16);
        sum += __shfl_xor(sum, 32);
        l_ = l_ * corr + sum;
        #pragma unroll
        for (int dt = 0; dt < 4; ++dt) oacc[dt] *= corr;
        // O^T += Vt * P^T
        __builtin_amdgcn_s_setprio(1);
        #pragma unroll
        for (int kh = 0; kh < 2; ++kh) {
          bf16x8 pb = *(const bf16x8*)&Pl[w][lo][((kh * 4 + g) ^ rs) * 8];
          #pragma unroll
          for (int dt = 0; dt < 4; ++dt) {
            bf16x8 va = *(const bf16x8*)&Vl[cur][dt * 16 + lo][((kh * 4 + g) ^ rs) * 8];
            oacc[dt] = mfma16(va, pb, oacc[dt]);
          }
        }
        __builtin_amdgcn_s_setprio(0);
      }
      // write next-step tile (regs loaded last iteration / prologue)
      if (stp + 1 < nsteps) {
        *(us8*)&Kl[cur ^ 1][srow][sgis] = kr0;
        *(us8*)&Kl[cur ^ 1][srow + 32][sgis] = kr1;
        *(us8*)&Vl[cur ^ 1][srow][sgis] = vr0;
        *(us8*)&Vl[cur ^ 1][srow + 32][sgis] = vr1;
      }
      __syncthreads();
      if (pf) { kr0 = nk0; kr1 = nk1; vr0 = nv0; vr1 = nv1; }
    }
    // epilogue: per-lane row t = tw + lo, d = dt*16 + g*4 + r
    float inv = 1.0f / l_;
    unsigned short* op = ao + ((size_t)(b * T_ + tw + lo)) * E_ + h * 64;
    #pragma unroll
    for (int dt = 0; dt < 4; ++dt) {
      us4 pk;
      #pragma unroll
      for (int r = 0; r < 4; ++r) pk[r] = f2b(oacc[dt][r] * inv);
      *(us4*)(op + dt * 16 + g * 4) = pk;
    }
  }
}

// ---------------- output projection: out = AO * Wp^T + bp ----------------
// grid: (4096/128=32, 1024/64=16), block 256 (2x2 waves of 64x32),
// bf16 Wp, 2-buffer 1-barrier pipeline.
__launch_bounds__(256)
__global__ void proj_kernel(const unsigned short* __restrict__ ao,
                            const unsigned short* __restrict__ wpb,
                            const float* __restrict__ bp,
                            float* __restrict__ out)
{
  const int m0 = blockIdx.x * 128;
  const int n0 = blockIdx.y * 64;
  __shared__ unsigned short Al[2][128][40];
  __shared__ unsigned short Bl[2][64][40];
  const int tid = threadIdx.x, w = tid >> 6, lane = tid & 63, lo = lane & 15, g = lane >> 4;
  const int wr = (w >> 1) * 64, wc = (w & 1) * 32;
  f32x4 zero4 = {0.f, 0.f, 0.f, 0.f};
  f32x4 acc[4][2];
  #pragma unroll
  for (int i = 0; i < 4; ++i)
    #pragma unroll
    for (int j = 0; j < 2; ++j) acc[i][j] = zero4;

  const int arow = tid >> 1, acol = (tid & 1) * 16;
  const int brow = tid >> 2, bcol = (tid & 3) * 8;
  const unsigned short* abase = ao + (size_t)(m0 + arow) * 1024 + acol;
  const unsigned short* bbase = wpb + (size_t)(n0 + brow) * 1024 + bcol;

  // prologue: k=0 staged, k=1 regs loaded
  us8 a0 = *(const us8*)(abase);
  us8 a1 = *(const us8*)(abase + 8);
  us8 b0 = *(const us8*)(bbase);
  *(us8*)&Al[0][arow][acol] = a0;
  *(us8*)&Al[0][arow][acol + 8] = a1;
  *(us8*)&Bl[0][brow][bcol] = b0;
  a0 = *(const us8*)(abase + 32);
  a1 = *(const us8*)(abase + 40);
  b0 = *(const us8*)(bbase + 32);
  __syncthreads();

  for (int it = 0; it < 32; ++it) {
    const int cur = it & 1;
    us8 na0, na1, nb0;
    const bool pf = (it + 2 < 32);
    if (pf) {
      const int kn = (it + 2) * 32;
      na0 = *(const us8*)(abase + kn);
      na1 = *(const us8*)(abase + kn + 8);
      nb0 = *(const us8*)(bbase + kn);
    }
    bf16x8 af[4], bfr[2];
    #pragma unroll
    for (int i = 0; i < 4; ++i) af[i] = *(const bf16x8*)&Al[cur][wr + i * 16 + lo][g * 8];
    #pragma unroll
    for (int j = 0; j < 2; ++j) bfr[j] = *(const bf16x8*)&Bl[cur][wc + j * 16 + lo][g * 8];
    __builtin_amdgcn_s_setprio(1);
    #pragma unroll
    for (int i = 0; i < 4; ++i)
      #pragma unroll
      for (int j = 0; j < 2; ++j)
        acc[i][j] = mfma16(af[i], bfr[j], acc[i][j]);
    __builtin_amdgcn_s_setprio(0);
    if (it + 1 < 32) {
      *(us8*)&Al[cur ^ 1][arow][acol] = a0;
      *(us8*)&Al[cur ^ 1][arow][acol + 8] = a1;
      *(us8*)&Bl[cur ^ 1][brow][bcol] = b0;
    }
    __syncthreads();
    if (pf) { a0 = na0; a1 = na1; b0 = nb0; }
  }
  #pragma unroll
  for (int j = 0; j < 2; ++j) {
    int n = n0 + wc + j * 16 + lo;
    float bias = bp[n];
    #pragma unroll
    for (int i = 0; i < 4; ++i) {
      #pragma unroll
      for (int r = 0; r < 4; ++r)
        out[(size_t)(m0 + wr + i * 16 + g * 4 + r) * 1024 + n] = acc[i][j][r] + bias;
    }
  }
}

extern "C" void kernel_launch(void* const* d_in, const int* in_sizes, int n_in,
                              void* d_out, int out_size, void* d_ws, size_t ws_size,
                              hipStream_t stream)
{
  const float* x  = (const float*)d_in[0];
  const float* Wq = (const float*)d_in[2];
  const float* bq = (const float*)d_in[3];
  const float* Wk = (const float*)d_in[4];
  const float* bk = (const float*)d_in[5];
  const float* Wv = (const float*)d_in[6];
  const float* bv = (const float*)d_in[7];
  const float* Wp = (const float*)d_in[8];
  const float* bp = (const float*)d_in[9];
  float* out = (float*)d_out;

  char* ws = (char*)d_ws;
  const size_t SZ = (size_t)2 * 16 * 2048 * 64 * 2;  // 8 MB per bf16 tensor
  unsigned short* q  = (unsigned short*)(ws);
  unsigned short* kb = (unsigned short*)(ws + SZ);
  unsigned short* vt = (unsigned short*)(ws + 2 * SZ);
  unsigned short* ao = (unsigned short*)(ws + 3 * SZ);
  // overlays (stream-ordered, no extra ws):
  //  - wq/wk/wv bf16 live in ao region (flash overwrites ao AFTER qkv read them)
  unsigned short* wqb = ao;                  // 128 KB
  unsigned short* wkb = ao + 65536;
  unsigned short* wvb = ao + 131072;
  //  - wp bf16 lives in q region (wpcvt runs AFTER flash finished reading q)
  unsigned short* wpb = q;                   // 2 MB

  wcvt_kernel<<<dim3(192), 256, 0, stream>>>(Wq, Wk, Wv, wqb, wkb, wvb);
  qkv_kernel<<<dim3(32, 16), 256, 0, stream>>>(x, wqb, bq, wkb, bk, wvb, bv, q, kb, vt);
  flash_kernel<<<dim3(32, 16), 256, 0, stream>>>(q, kb, vt, ao);
  wpcvt_kernel<<<dim3(1024), 256, 0, stream>>>(Wp, wpb);
  proj_kernel<<<dim3(32, 16), 256, 0, stream>>>(ao, wpb, bp, out);
}